// Round 1
// baseline (99.379 us; speedup 1.0000x reference)
//
#include <hip/hip_runtime.h>
#include <hip/hip_bf16.h>

typedef __attribute__((ext_vector_type(8))) __bf16 bf16x8;
typedef __attribute__((ext_vector_type(4))) float f32x4;
typedef __attribute__((ext_vector_type(8))) unsigned short ushort8;

__device__ __forceinline__ unsigned short f2bf(float f) {
  unsigned u = __builtin_bit_cast(unsigned, f);
  u += 0x7FFFu + ((u >> 16) & 1u);   // round-to-nearest-even
  return (unsigned short)(u >> 16);
}

__device__ __forceinline__ void gload_lds16(const void* g, void* l) {
  __builtin_amdgcn_global_load_lds(
      (const __attribute__((address_space(1))) void*)g,
      (__attribute__((address_space(3))) void*)l, 16, 0, 0);
}

// ---------------- f32 -> bf16 convert, 8 elems/thread ----------------
__global__ void cvt_bf16_kernel(const float* __restrict__ src,
                                unsigned short* __restrict__ dst, int n8) {
  int i = blockIdx.x * blockDim.x + threadIdx.x;
  if (i >= n8) return;
  const float4* s4 = reinterpret_cast<const float4*>(src) + 2 * (size_t)i;
  float4 a = s4[0], b = s4[1];
  ushort8 o;
  o[0] = f2bf(a.x); o[1] = f2bf(a.y); o[2] = f2bf(a.z); o[3] = f2bf(a.w);
  o[4] = f2bf(b.x); o[5] = f2bf(b.y); o[6] = f2bf(b.z); o[7] = f2bf(b.w);
  *(reinterpret_cast<ushort8*>(dst) + i) = o;
}

// ------- transpose + convert: src[rows][cols] f32 -> dst[cols][rows] bf16 ----
__global__ void transpose_bf16_kernel(const float* __restrict__ src,
                                      unsigned short* __restrict__ dst,
                                      int rows, int cols) {
  __shared__ float tile[32][33];
  int bx = blockIdx.x * 32;  // col base in src
  int by = blockIdx.y * 32;  // row base in src
  int tx = threadIdx.x, ty = threadIdx.y;
  for (int i = ty; i < 32; i += 8)
    tile[i][tx] = src[(size_t)(by + i) * cols + bx + tx];
  __syncthreads();
  for (int i = ty; i < 32; i += 8)
    dst[(size_t)(bx + i) * rows + by + tx] = f2bf(tile[tx][i]);
}

// ---------------- bf16 GEMM: C[M,N] = A[M,K] * Bt[N,K]^T ----------------
// EPI 0: outf = acc + e0[col]                      (s = S + context@W)
// EPI 1: outb = bf16(acc * e0[row*N+col])          (xus = xu * s)
// EPI 2: outf = relu(acc + e0[col])                (final output)
template <int FM, int FN, int EPI>
__global__ __launch_bounds__(256) void gemm_bt_kernel(
    const unsigned short* __restrict__ A, const unsigned short* __restrict__ Bt,
    int M, int N, int K, const float* __restrict__ e0,
    float* __restrict__ outf, unsigned short* __restrict__ outb) {
  constexpr int BM = 32 * FM, BN = 32 * FN, BK = 64;
  __shared__ unsigned short lds[(BM + BN) * BK];
  unsigned short* As = lds;
  unsigned short* Bs = lds + BM * BK;

  const int tid = threadIdx.x;
  const int wid = tid >> 6;
  const int lane = tid & 63;
  const int wr = wid >> 1, wc = wid & 1;

  const int nbn = N / BN;
  const int brow = ((int)blockIdx.x / nbn) * BM;
  const int bcol = ((int)blockIdx.x % nbn) * BN;

  f32x4 zero = {0.f, 0.f, 0.f, 0.f};
  f32x4 acc[FM][FN];
#pragma unroll
  for (int m = 0; m < FM; ++m)
#pragma unroll
    for (int n = 0; n < FN; ++n) acc[m][n] = zero;

  // ---- staging geometry: each issue = 8 rows x 64 bf16 = 1KB, linear LDS ----
  // XOR swizzle (both-sides): source fetches logical chunk (p ^ row&7) into
  // physical chunk p; reads use physical = logical ^ (row&7).
  const int lr = lane >> 3;                      // row within 8-row issue
  const int swzc = ((lane & 7) ^ lr) * 8;        // pre-swizzled source col (elems)
  const unsigned short* Agp = A + (size_t)(brow + wid * (BM / 4) + lr) * K + swzc;
  const unsigned short* Bgp = Bt + (size_t)(bcol + wid * (BN / 4) + lr) * K + swzc;
  unsigned short* AsW = As + wid * (BM / 4) * 64;
  unsigned short* BsW = Bs + wid * (BN / 4) * 64;

  const int frow = lane & 15;
  const int fhi = lane >> 4;  // 0..3
  const int fx = lane & 7;    // == (frag row) & 7

  for (int kt = 0; kt < K; kt += BK) {
#pragma unroll
    for (int i = 0; i < BM / 32; ++i)
      gload_lds16(Agp + kt + (size_t)i * 8 * K, AsW + i * 512);
#pragma unroll
    for (int i = 0; i < BN / 32; ++i)
      gload_lds16(Bgp + kt + (size_t)i * 8 * K, BsW + i * 512);
    asm volatile("s_waitcnt vmcnt(0)" ::: "memory");
    __syncthreads();

#pragma unroll
    for (int ks = 0; ks < 2; ++ks) {
      bf16x8 af[FM], bg[FN];
#pragma unroll
      for (int m = 0; m < FM; ++m) {
        int row = wr * FM * 16 + m * 16 + frow;
        int c = (ks * 4 + fhi) ^ fx;  // physical chunk
        af[m] = *reinterpret_cast<const bf16x8*>(As + row * 64 + c * 8);
      }
#pragma unroll
      for (int n = 0; n < FN; ++n) {
        int row = wc * FN * 16 + n * 16 + frow;
        int c = (ks * 4 + fhi) ^ fx;
        bg[n] = *reinterpret_cast<const bf16x8*>(Bs + row * 64 + c * 8);
      }
#pragma unroll
      for (int m = 0; m < FM; ++m)
#pragma unroll
        for (int n = 0; n < FN; ++n)
          acc[m][n] = __builtin_amdgcn_mfma_f32_16x16x32_bf16(af[m], bg[n],
                                                              acc[m][n], 0, 0, 0);
    }
    __syncthreads();
  }

  // ---- epilogue: D col = lane&15, row = (lane>>4)*4 + j ----
#pragma unroll
  for (int m = 0; m < FM; ++m) {
    int gr0 = brow + wr * FM * 16 + m * 16 + fhi * 4;
#pragma unroll
    for (int n = 0; n < FN; ++n) {
      int gc = bcol + wc * FN * 16 + n * 16 + frow;
#pragma unroll
      for (int j = 0; j < 4; ++j) {
        size_t idx = (size_t)(gr0 + j) * N + gc;
        float v = acc[m][n][j];
        if constexpr (EPI == 0) {
          outf[idx] = v + e0[gc];
        } else if constexpr (EPI == 1) {
          outb[idx] = f2bf(v * e0[idx]);
        } else {
          v += e0[gc];
          outf[idx] = v > 0.f ? v : 0.f;
        }
      }
    }
  }
}

extern "C" void kernel_launch(void* const* d_in, const int* in_sizes, int n_in,
                              void* d_out, int out_size, void* d_ws, size_t ws_size,
                              hipStream_t stream) {
  constexpr int Bm = 2048, Nn = 4096, Cc = 1024, UU = 4096, RR = 512;
  const float* inputs  = (const float*)d_in[0];
  const float* context = (const float*)d_in[1];
  const float* U       = (const float*)d_in[2];
  const float* S       = (const float*)d_in[3];
  const float* V       = (const float*)d_in[4];
  const float* W       = (const float*)d_in[5];
  const float* bias    = (const float*)d_in[6];
  float* out = (float*)d_out;

  char* p = (char*)d_ws;
  unsigned short* inb  = (unsigned short*)p; p += (size_t)Bm * Nn * 2;  // 16 MB
  unsigned short* ctxb = (unsigned short*)p; p += (size_t)Bm * Cc * 2;  //  4 MB
  unsigned short* Ut   = (unsigned short*)p; p += (size_t)RR * Nn * 2;  //  4 MB
  unsigned short* Wt   = (unsigned short*)p; p += (size_t)RR * Cc * 2;  //  1 MB
  unsigned short* Vb   = (unsigned short*)p; p += (size_t)UU * RR * 2;  //  4 MB
  float*          sbuf = (float*)p;          p += (size_t)Bm * RR * 4;  //  4 MB
  unsigned short* xus  = (unsigned short*)p; p += (size_t)Bm * RR * 2;  //  2 MB

  // conversions (exact grids; all counts divisible)
  cvt_bf16_kernel<<<Bm * Nn / 8 / 256, 256, 0, stream>>>(inputs, inb, Bm * Nn / 8);
  cvt_bf16_kernel<<<Bm * Cc / 8 / 256, 256, 0, stream>>>(context, ctxb, Bm * Cc / 8);
  cvt_bf16_kernel<<<UU * RR / 8 / 256, 256, 0, stream>>>(V, Vb, UU * RR / 8);
  transpose_bf16_kernel<<<dim3(RR / 32, Nn / 32), dim3(32, 8), 0, stream>>>(U, Ut, Nn, RR);
  transpose_bf16_kernel<<<dim3(RR / 32, Cc / 32), dim3(32, 8), 0, stream>>>(W, Wt, Cc, RR);

  // s = S + context @ W        (M=2048, N=512, K=1024) -> f32
  gemm_bt_kernel<2, 2, 0><<<(Bm / 64) * (RR / 64), 256, 0, stream>>>(
      ctxb, Wt, Bm, RR, Cc, S, sbuf, nullptr);
  // xus = (inputs @ U) * s     (M=2048, N=512, K=4096) -> bf16
  gemm_bt_kernel<2, 2, 1><<<(Bm / 64) * (RR / 64), 256, 0, stream>>>(
      inb, Ut, Bm, RR, Nn, sbuf, nullptr, xus);
  // out = relu(xus @ V^T + b)  (M=2048, N=4096, K=512) -> f32
  gemm_bt_kernel<4, 4, 2><<<(Bm / 128) * (UU / 128), 256, 0, stream>>>(
      xus, Vb, Bm, UU, RR, bias, out, nullptr);
}

// Round 2
// 76.934 us; speedup vs baseline: 1.2917x; 1.2917x over previous
//
#include <hip/hip_runtime.h>
#include <hip/hip_bf16.h>

typedef __attribute__((ext_vector_type(8))) __bf16 bf16x8;
typedef __attribute__((ext_vector_type(4))) float f32x4;
typedef __attribute__((ext_vector_type(8))) unsigned short ushort8;
typedef __attribute__((ext_vector_type(4))) unsigned short ushort4v;

__device__ __forceinline__ unsigned short f2bf(float f) {
  unsigned u = __builtin_bit_cast(unsigned, f);
  u += 0x7FFFu + ((u >> 16) & 1u);   // round-to-nearest-even
  return (unsigned short)(u >> 16);
}

__device__ __forceinline__ void gload_lds16(const void* g, void* l) {
  __builtin_amdgcn_global_load_lds(
      (const __attribute__((address_space(1))) void*)g,
      (__attribute__((address_space(3))) void*)l, 16, 0, 0);
}

// ---------------- f32 -> bf16 convert, 8 elems/thread ----------------
__global__ void cvt_bf16_kernel(const float* __restrict__ src,
                                unsigned short* __restrict__ dst, int n8) {
  int i = blockIdx.x * blockDim.x + threadIdx.x;
  if (i >= n8) return;
  const float4* s4 = reinterpret_cast<const float4*>(src) + 2 * (size_t)i;
  float4 a = s4[0], b = s4[1];
  ushort8 o;
  o[0] = f2bf(a.x); o[1] = f2bf(a.y); o[2] = f2bf(a.z); o[3] = f2bf(a.w);
  o[4] = f2bf(b.x); o[5] = f2bf(b.y); o[6] = f2bf(b.z); o[7] = f2bf(b.w);
  *(reinterpret_cast<ushort8*>(dst) + i) = o;
}

// ------- transpose + convert: src[rows][cols] f32 -> dst[cols][rows] bf16 ----
__global__ void transpose_bf16_kernel(const float* __restrict__ src,
                                      unsigned short* __restrict__ dst,
                                      int rows, int cols) {
  __shared__ float tile[32][33];
  int bx = blockIdx.x * 32;  // col base in src
  int by = blockIdx.y * 32;  // row base in src
  int tx = threadIdx.x, ty = threadIdx.y;
  for (int i = ty; i < 32; i += 8)
    tile[i][tx] = src[(size_t)(by + i) * cols + bx + tx];
  __syncthreads();
  for (int i = ty; i < 32; i += 8)
    dst[(size_t)(bx + i) * rows + by + tx] = f2bf(tile[tx][i]);
}

// ---------------- bf16 GEMM: C[M,N] = A[M,K] * Bt[N,K]^T ----------------
// 2-phase double-buffered pipeline: stage(next) -> compute(cur) -> barrier.
// EPI 2: outf = relu(acc + e0[col])  (final output)
// EPI 3: split-K partial: outf[split*M*N + idx] = acc
template <int FM, int FN, int EPI>
__global__ __launch_bounds__(256) void gemm_bt_kernel(
    const unsigned short* __restrict__ A, const unsigned short* __restrict__ Bt,
    int M, int N, int lda, int kchunk, const float* __restrict__ e0,
    float* __restrict__ outf, unsigned short* __restrict__ outb) {
  constexpr int BM = 32 * FM, BN = 32 * FN, BK = 64;
  __shared__ unsigned short lds[2][(BM + BN) * BK];

  const int tid = threadIdx.x;
  const int wid = tid >> 6;
  const int lane = tid & 63;
  const int wr = wid >> 1, wc = wid & 1;

  const int nbn = N / BN;
  const int brow = ((int)blockIdx.x / nbn) * BM;
  const int bcol = ((int)blockIdx.x % nbn) * BN;
  const int k0 = (int)blockIdx.y * kchunk;

  f32x4 zero = {0.f, 0.f, 0.f, 0.f};
  f32x4 acc[FM][FN];
#pragma unroll
  for (int m = 0; m < FM; ++m)
#pragma unroll
    for (int n = 0; n < FN; ++n) acc[m][n] = zero;

  // ---- staging geometry: each issue = 8 rows x 64 bf16 = 1KB, linear LDS ----
  // XOR swizzle (both-sides): source fetches logical chunk ((lane&7)^lr) into
  // physical chunk (lane&7); reads use physical = logical ^ (row&7).
  const int lr = lane >> 3;                      // row within 8-row issue
  const int swzc = ((lane & 7) ^ lr) * 8;        // pre-swizzled source col (elems)
  const unsigned short* Agp =
      A + (size_t)(brow + wid * (BM / 4) + lr) * lda + swzc + k0;
  const unsigned short* Bgp =
      Bt + (size_t)(bcol + wid * (BN / 4) + lr) * lda + swzc + k0;

  const int frow = lane & 15;
  const int fhi = lane >> 4;  // 0..3
  const int fx = lane & 7;    // == (frag row) & 7

  const int nsteps = kchunk / BK;

  auto stage = [&](int b, int kofs) {
    unsigned short* AsW = lds[b] + wid * (BM / 4) * 64;
    unsigned short* BsW = lds[b] + BM * BK + wid * (BN / 4) * 64;
#pragma unroll
    for (int i = 0; i < BM / 32; ++i)
      gload_lds16(Agp + kofs + (size_t)i * 8 * lda, AsW + i * 512);
#pragma unroll
    for (int i = 0; i < BN / 32; ++i)
      gload_lds16(Bgp + kofs + (size_t)i * 8 * lda, BsW + i * 512);
  };

  // prologue: stage tile 0, drain, barrier
  stage(0, 0);
  __syncthreads();   // implicit vmcnt(0) drain

  int cur = 0;
  for (int t = 0; t < nsteps; ++t) {
    if (t + 1 < nsteps) stage(cur ^ 1, (t + 1) * BK);  // in flight during MFMA
    const unsigned short* As = lds[cur];
    const unsigned short* Bs = lds[cur] + BM * BK;
#pragma unroll
    for (int ks = 0; ks < 2; ++ks) {
      bf16x8 af[FM], bg[FN];
#pragma unroll
      for (int m = 0; m < FM; ++m) {
        int row = wr * FM * 16 + m * 16 + frow;
        int c = (ks * 4 + fhi) ^ fx;  // physical chunk
        af[m] = *reinterpret_cast<const bf16x8*>(As + row * 64 + c * 8);
      }
#pragma unroll
      for (int n = 0; n < FN; ++n) {
        int row = wc * FN * 16 + n * 16 + frow;
        int c = (ks * 4 + fhi) ^ fx;
        bg[n] = *reinterpret_cast<const bf16x8*>(Bs + row * 64 + c * 8);
      }
#pragma unroll
      for (int m = 0; m < FM; ++m)
#pragma unroll
        for (int n = 0; n < FN; ++n)
          acc[m][n] = __builtin_amdgcn_mfma_f32_16x16x32_bf16(af[m], bg[n],
                                                              acc[m][n], 0, 0, 0);
    }
    __syncthreads();  // drains vmcnt(0): next buffer ready; cur readers done
    cur ^= 1;
  }

  // ---- epilogue: D col = lane&15, row = (lane>>4)*4 + j ----
#pragma unroll
  for (int m = 0; m < FM; ++m) {
    int gr0 = brow + wr * FM * 16 + m * 16 + fhi * 4;
#pragma unroll
    for (int n = 0; n < FN; ++n) {
      int gc = bcol + wc * FN * 16 + n * 16 + frow;
#pragma unroll
      for (int j = 0; j < 4; ++j) {
        size_t idx = (size_t)(gr0 + j) * N + gc;
        float v = acc[m][n][j];
        if constexpr (EPI == 2) {
          v += e0[gc];
          outf[idx] = v > 0.f ? v : 0.f;
        } else {
          outf[(size_t)blockIdx.y * M * N + idx] = v;
        }
      }
    }
  }
}

// ---- fused split-K reduce: xus = bf16((sum p1) * (S + sum p0)) ----
__global__ void reduce_mul_kernel(const float* __restrict__ p1,  // [4][MN]
                                  const float* __restrict__ p0,  // [2][MN]
                                  const float* __restrict__ Svec,  // [512]
                                  unsigned short* __restrict__ xus, int MN) {
  int i = blockIdx.x * blockDim.x + threadIdx.x;
  size_t base = (size_t)i * 4;
  if (base >= (size_t)MN) return;
  float4 a = *reinterpret_cast<const float4*>(p1 + base);
  float4 b = *reinterpret_cast<const float4*>(p1 + (size_t)MN + base);
  float4 c = *reinterpret_cast<const float4*>(p1 + 2 * (size_t)MN + base);
  float4 d = *reinterpret_cast<const float4*>(p1 + 3 * (size_t)MN + base);
  float4 s0 = *reinterpret_cast<const float4*>(p0 + base);
  float4 s1 = *reinterpret_cast<const float4*>(p0 + (size_t)MN + base);
  float4 sv = *reinterpret_cast<const float4*>(Svec + (base & 511));
  float4 xu, s;
  xu.x = (a.x + b.x) + (c.x + d.x);  s.x = s0.x + s1.x + sv.x;
  xu.y = (a.y + b.y) + (c.y + d.y);  s.y = s0.y + s1.y + sv.y;
  xu.z = (a.z + b.z) + (c.z + d.z);  s.z = s0.z + s1.z + sv.z;
  xu.w = (a.w + b.w) + (c.w + d.w);  s.w = s0.w + s1.w + sv.w;
  ushort4v o;
  o[0] = f2bf(xu.x * s.x);
  o[1] = f2bf(xu.y * s.y);
  o[2] = f2bf(xu.z * s.z);
  o[3] = f2bf(xu.w * s.w);
  *reinterpret_cast<ushort4v*>(xus + base) = o;
}

extern "C" void kernel_launch(void* const* d_in, const int* in_sizes, int n_in,
                              void* d_out, int out_size, void* d_ws, size_t ws_size,
                              hipStream_t stream) {
  constexpr int Bm = 2048, Nn = 4096, Cc = 1024, UU = 4096, RR = 512;
  const float* inputs  = (const float*)d_in[0];
  const float* context = (const float*)d_in[1];
  const float* U       = (const float*)d_in[2];
  const float* S       = (const float*)d_in[3];
  const float* V       = (const float*)d_in[4];
  const float* W       = (const float*)d_in[5];
  const float* bias    = (const float*)d_in[6];
  float* out = (float*)d_out;

  char* p = (char*)d_ws;
  unsigned short* inb  = (unsigned short*)p; p += (size_t)Bm * Nn * 2;      // 16 MB
  unsigned short* ctxb = (unsigned short*)p; p += (size_t)Bm * Cc * 2;      //  4 MB
  unsigned short* Ut   = (unsigned short*)p; p += (size_t)RR * Nn * 2;      //  4 MB
  unsigned short* Wt   = (unsigned short*)p; p += (size_t)RR * Cc * 2;      //  1 MB
  unsigned short* Vb   = (unsigned short*)p; p += (size_t)UU * RR * 2;      //  4 MB
  float*          p0   = (float*)p;          p += (size_t)2 * Bm * RR * 4;  //  8 MB
  float*          p1   = (float*)p;          p += (size_t)4 * Bm * RR * 4;  // 16 MB
  unsigned short* xus  = (unsigned short*)p; p += (size_t)Bm * RR * 2;      //  2 MB

  // conversions (exact grids; all counts divisible)
  cvt_bf16_kernel<<<Bm * Nn / 8 / 256, 256, 0, stream>>>(inputs, inb, Bm * Nn / 8);
  cvt_bf16_kernel<<<Bm * Cc / 8 / 256, 256, 0, stream>>>(context, ctxb, Bm * Cc / 8);
  cvt_bf16_kernel<<<UU * RR / 8 / 256, 256, 0, stream>>>(V, Vb, UU * RR / 8);
  transpose_bf16_kernel<<<dim3(RR / 32, Nn / 32), dim3(32, 8), 0, stream>>>(U, Ut, Nn, RR);
  transpose_bf16_kernel<<<dim3(RR / 32, Cc / 32), dim3(32, 8), 0, stream>>>(W, Wt, Cc, RR);

  // partials of context @ W    (M=2048, N=512, K=1024, split 2)
  gemm_bt_kernel<2, 2, 3><<<dim3((Bm / 64) * (RR / 64), 2), 256, 0, stream>>>(
      ctxb, Wt, Bm, RR, Cc, Cc / 2, nullptr, p0, nullptr);
  // partials of inputs @ U     (M=2048, N=512, K=4096, split 4)
  gemm_bt_kernel<2, 2, 3><<<dim3((Bm / 64) * (RR / 64), 4), 256, 0, stream>>>(
      inb, Ut, Bm, RR, Nn, Nn / 4, nullptr, p1, nullptr);
  // xus = bf16((sum p1) * (S + sum p0))
  reduce_mul_kernel<<<Bm * RR / 4 / 256, 256, 0, stream>>>(p1, p0, S, xus, Bm * RR);
  // out = relu(xus @ V^T + b)  (M=2048, N=4096, K=512)
  gemm_bt_kernel<4, 4, 2><<<dim3((Bm / 128) * (UU / 128), 1), 256, 0, stream>>>(
      xus, Vb, Bm, UU, RR, RR, bias, out, nullptr);
}

// Round 3
// 68.567 us; speedup vs baseline: 1.4494x; 1.1220x over previous
//
#include <hip/hip_runtime.h>
#include <hip/hip_bf16.h>

typedef __attribute__((ext_vector_type(8))) __bf16 bf16x8;
typedef __attribute__((ext_vector_type(4))) float f32x4;
typedef __attribute__((ext_vector_type(8))) unsigned short ushort8;
typedef __attribute__((ext_vector_type(4))) unsigned short ushort4v;

__device__ __forceinline__ unsigned short f2bf(float f) {
  unsigned u = __builtin_bit_cast(unsigned, f);
  u += 0x7FFFu + ((u >> 16) & 1u);   // round-to-nearest-even
  return (unsigned short)(u >> 16);
}

__device__ __forceinline__ void gload_lds16(const void* g, void* l) {
  __builtin_amdgcn_global_load_lds(
      (const __attribute__((address_space(1))) void*)g,
      (__attribute__((address_space(3))) void*)l, 16, 0, 0);
}

// ------- transpose + convert: src[rows][cols] f32 -> dst[cols][rows] bf16 ----
__global__ void transpose_bf16_kernel(const float* __restrict__ src,
                                      unsigned short* __restrict__ dst,
                                      int rows, int cols) {
  __shared__ float tile[32][33];
  int bx = blockIdx.x * 32;  // col base in src
  int by = blockIdx.y * 32;  // row base in src
  int tx = threadIdx.x, ty = threadIdx.y;
  for (int i = ty; i < 32; i += 8)
    tile[i][tx] = src[(size_t)(by + i) * cols + bx + tx];
  __syncthreads();
  for (int i = ty; i < 32; i += 8)
    dst[(size_t)(bx + i) * rows + by + tx] = f2bf(tile[tx][i]);
}

// ---------------- bf16 GEMM: C[M,N] = A[M,K] * Bt[N,K]^T ----------------
// Operands may be bf16 (global_load_lds staging) or f32 (reg-staged with
// fused f32->bf16 conversion: loads issued before MFMA, ds_write after).
// 2-phase double-buffered pipeline, one barrier per K-step.
// EPI 2: outf = relu(acc + e0[col])  (final output)
// EPI 3: split-K partial: outf[split*M*N + idx] = acc
template <int FM, int FN, int EPI, bool AF32, bool BF32>
__global__ __launch_bounds__(256) void gemm_bt_kernel(
    const void* __restrict__ Av, const void* __restrict__ Bv,
    int M, int N, int lda, int kchunk, const float* __restrict__ e0,
    float* __restrict__ outf, unsigned short* __restrict__ outb) {
  constexpr int BM = 32 * FM, BN = 32 * FN, BK = 64;
  constexpr int AI = BM / 32, BI = BN / 32;  // 1KB staging issues per wave
  __shared__ unsigned short lds[2][(BM + BN) * BK];

  const int tid = threadIdx.x;
  const int wid = tid >> 6;
  const int lane = tid & 63;
  const int wr = wid >> 1, wc = wid & 1;

  // XCD-aware bijective swizzle (gridDim.x % 8 == 0 for all our grids)
  const int nwg = gridDim.x;
  const int bid = (int)blockIdx.x;
  const int swz = (bid & 7) * (nwg >> 3) + (bid >> 3);

  const int nbn = N / BN;
  const int brow = (swz / nbn) * BM;
  const int bcol = (swz % nbn) * BN;
  const int k0 = (int)blockIdx.y * kchunk;

  f32x4 zero = {0.f, 0.f, 0.f, 0.f};
  f32x4 acc[FM][FN];
#pragma unroll
  for (int m = 0; m < FM; ++m)
#pragma unroll
    for (int n = 0; n < FN; ++n) acc[m][n] = zero;

  // ---- staging geometry: each issue = 8 rows x 64 bf16 = 1KB, linear LDS ----
  // XOR swizzle: physical chunk p at row r holds logical chunk p^ (r&7);
  // source col is pre-swizzled, read side applies ^ (row&7).
  const int lr = lane >> 3;                      // row within 8-row issue
  const int swzc = ((lane & 7) ^ lr) * 8;        // pre-swizzled source col (elems)
  const size_t arow = (size_t)(brow + wid * (BM / 4) + lr);
  const size_t brow_ = (size_t)(bcol + wid * (BN / 4) + lr);
  const float* Agf = (const float*)Av + arow * lda + swzc + k0;
  const unsigned short* Agh = (const unsigned short*)Av + arow * lda + swzc + k0;
  const float* Bgf = (const float*)Bv + brow_ * lda + swzc + k0;
  const unsigned short* Bgh = (const unsigned short*)Bv + brow_ * lda + swzc + k0;

  const int frow = lane & 15;
  const int fhi = lane >> 4;  // 0..3
  const int fx = lane & 7;    // == (frag row) & 7

  const int nsteps = kchunk / BK;

  float4 areg[AI][2];
  float4 breg[BI][2];

  auto stage_issue = [&](int b, int kofs) {
    if constexpr (AF32) {
#pragma unroll
      for (int i = 0; i < AI; ++i) {
        const float* s = Agf + kofs + (size_t)i * 8 * lda;
        areg[i][0] = *reinterpret_cast<const float4*>(s);
        areg[i][1] = *reinterpret_cast<const float4*>(s + 4);
      }
    } else {
      unsigned short* AsW = lds[b] + wid * (BM / 4) * 64;
#pragma unroll
      for (int i = 0; i < AI; ++i)
        gload_lds16(Agh + kofs + (size_t)i * 8 * lda, AsW + i * 512);
    }
    if constexpr (BF32) {
#pragma unroll
      for (int i = 0; i < BI; ++i) {
        const float* s = Bgf + kofs + (size_t)i * 8 * lda;
        breg[i][0] = *reinterpret_cast<const float4*>(s);
        breg[i][1] = *reinterpret_cast<const float4*>(s + 4);
      }
    } else {
      unsigned short* BsW = lds[b] + BM * BK + wid * (BN / 4) * 64;
#pragma unroll
      for (int i = 0; i < BI; ++i)
        gload_lds16(Bgh + kofs + (size_t)i * 8 * lda, BsW + i * 512);
    }
  };

  auto stage_write = [&](int b) {
    if constexpr (AF32) {
      unsigned short* AsW = lds[b] + wid * (BM / 4) * 64 + lane * 8;
#pragma unroll
      for (int i = 0; i < AI; ++i) {
        float4 x = areg[i][0], y = areg[i][1];
        ushort8 o;
        o[0] = f2bf(x.x); o[1] = f2bf(x.y); o[2] = f2bf(x.z); o[3] = f2bf(x.w);
        o[4] = f2bf(y.x); o[5] = f2bf(y.y); o[6] = f2bf(y.z); o[7] = f2bf(y.w);
        *reinterpret_cast<ushort8*>(AsW + i * 512) = o;
      }
    }
    if constexpr (BF32) {
      unsigned short* BsW = lds[b] + BM * BK + wid * (BN / 4) * 64 + lane * 8;
#pragma unroll
      for (int i = 0; i < BI; ++i) {
        float4 x = breg[i][0], y = breg[i][1];
        ushort8 o;
        o[0] = f2bf(x.x); o[1] = f2bf(x.y); o[2] = f2bf(x.z); o[3] = f2bf(x.w);
        o[4] = f2bf(y.x); o[5] = f2bf(y.y); o[6] = f2bf(y.z); o[7] = f2bf(y.w);
        *reinterpret_cast<ushort8*>(BsW + i * 512) = o;
      }
    }
  };

  // prologue: stage tile 0
  stage_issue(0, 0);
  stage_write(0);
  __syncthreads();   // implicit vmcnt(0)+lgkmcnt(0) drain

  int cur = 0;
  for (int t = 0; t < nsteps; ++t) {
    bool has_next = (t + 1 < nsteps);
    if (has_next) stage_issue(cur ^ 1, (t + 1) * BK);  // in flight during MFMA
    const unsigned short* As = lds[cur];
    const unsigned short* Bs = lds[cur] + BM * BK;
#pragma unroll
    for (int ks = 0; ks < 2; ++ks) {
      bf16x8 af[FM], bg[FN];
#pragma unroll
      for (int m = 0; m < FM; ++m) {
        int row = wr * FM * 16 + m * 16 + frow;
        int c = (ks * 4 + fhi) ^ fx;  // physical chunk
        af[m] = *reinterpret_cast<const bf16x8*>(As + row * 64 + c * 8);
      }
#pragma unroll
      for (int n = 0; n < FN; ++n) {
        int row = wc * FN * 16 + n * 16 + frow;
        int c = (ks * 4 + fhi) ^ fx;
        bg[n] = *reinterpret_cast<const bf16x8*>(Bs + row * 64 + c * 8);
      }
#pragma unroll
      for (int m = 0; m < FM; ++m)
#pragma unroll
        for (int n = 0; n < FN; ++n)
          acc[m][n] = __builtin_amdgcn_mfma_f32_16x16x32_bf16(af[m], bg[n],
                                                              acc[m][n], 0, 0, 0);
    }
    if (has_next) stage_write(cur ^ 1);  // cvt+ds_write after MFMA hid latency
    __syncthreads();  // drains vmcnt(0)/lgkmcnt(0): next buffer ready
    cur ^= 1;
  }

  // ---- epilogue: D col = lane&15, row = (lane>>4)*4 + j ----
#pragma unroll
  for (int m = 0; m < FM; ++m) {
    int gr0 = brow + wr * FM * 16 + m * 16 + fhi * 4;
#pragma unroll
    for (int n = 0; n < FN; ++n) {
      int gc = bcol + wc * FN * 16 + n * 16 + frow;
#pragma unroll
      for (int j = 0; j < 4; ++j) {
        size_t idx = (size_t)(gr0 + j) * N + gc;
        float v = acc[m][n][j];
        if constexpr (EPI == 2) {
          v += e0[gc];
          outf[idx] = v > 0.f ? v : 0.f;
        } else {
          outf[(size_t)blockIdx.y * M * N + idx] = v;
        }
      }
    }
  }
}

// ---- fused split-K reduce: xus = bf16((sum p1) * (S + sum p0)) ----
__global__ void reduce_mul_kernel(const float* __restrict__ p1,  // [4][MN]
                                  const float* __restrict__ p0,  // [2][MN]
                                  const float* __restrict__ Svec,  // [512]
                                  unsigned short* __restrict__ xus, int MN) {
  int i = blockIdx.x * blockDim.x + threadIdx.x;
  size_t base = (size_t)i * 4;
  if (base >= (size_t)MN) return;
  float4 a = *reinterpret_cast<const float4*>(p1 + base);
  float4 b = *reinterpret_cast<const float4*>(p1 + (size_t)MN + base);
  float4 c = *reinterpret_cast<const float4*>(p1 + 2 * (size_t)MN + base);
  float4 d = *reinterpret_cast<const float4*>(p1 + 3 * (size_t)MN + base);
  float4 s0 = *reinterpret_cast<const float4*>(p0 + base);
  float4 s1 = *reinterpret_cast<const float4*>(p0 + (size_t)MN + base);
  float4 sv = *reinterpret_cast<const float4*>(Svec + (base & 511));
  float4 xu, s;
  xu.x = (a.x + b.x) + (c.x + d.x);  s.x = s0.x + s1.x + sv.x;
  xu.y = (a.y + b.y) + (c.y + d.y);  s.y = s0.y + s1.y + sv.y;
  xu.z = (a.z + b.z) + (c.z + d.z);  s.z = s0.z + s1.z + sv.z;
  xu.w = (a.w + b.w) + (c.w + d.w);  s.w = s0.w + s1.w + sv.w;
  ushort4v o;
  o[0] = f2bf(xu.x * s.x);
  o[1] = f2bf(xu.y * s.y);
  o[2] = f2bf(xu.z * s.z);
  o[3] = f2bf(xu.w * s.w);
  *reinterpret_cast<ushort4v*>(xus + base) = o;
}

extern "C" void kernel_launch(void* const* d_in, const int* in_sizes, int n_in,
                              void* d_out, int out_size, void* d_ws, size_t ws_size,
                              hipStream_t stream) {
  constexpr int Bm = 2048, Nn = 4096, Cc = 1024, UU = 4096, RR = 512;
  const float* inputs  = (const float*)d_in[0];
  const float* context = (const float*)d_in[1];
  const float* U       = (const float*)d_in[2];
  const float* S       = (const float*)d_in[3];
  const float* V       = (const float*)d_in[4];
  const float* W       = (const float*)d_in[5];
  const float* bias    = (const float*)d_in[6];
  float* out = (float*)d_out;

  char* p = (char*)d_ws;
  unsigned short* Ut   = (unsigned short*)p; p += (size_t)RR * Nn * 2;      //  4 MB
  unsigned short* Wt   = (unsigned short*)p; p += (size_t)RR * Cc * 2;      //  1 MB
  float*          p0   = (float*)p;          p += (size_t)2 * Bm * RR * 4;  //  8 MB
  float*          p1   = (float*)p;          p += (size_t)4 * Bm * RR * 4;  // 16 MB
  unsigned short* xus  = (unsigned short*)p; p += (size_t)Bm * RR * 2;      //  2 MB

  // B-operand transposes (small): U[N,R] -> Ut[R,N], W[C,R] -> Wt[R,C]
  transpose_bf16_kernel<<<dim3(RR / 32, Nn / 32), dim3(32, 8), 0, stream>>>(U, Ut, Nn, RR);
  transpose_bf16_kernel<<<dim3(RR / 32, Cc / 32), dim3(32, 8), 0, stream>>>(W, Wt, Cc, RR);

  // partials of context @ W    (M=2048, N=512, K=1024, split 2; A f32 fused-cvt)
  gemm_bt_kernel<2, 2, 3, true, false>
      <<<dim3((Bm / 64) * (RR / 64), 2), 256, 0, stream>>>(
          context, Wt, Bm, RR, Cc, Cc / 2, nullptr, p0, nullptr);
  // partials of inputs @ U     (M=2048, N=512, K=4096, split 4; A f32 fused-cvt)
  gemm_bt_kernel<2, 2, 3, true, false>
      <<<dim3((Bm / 64) * (RR / 64), 4), 256, 0, stream>>>(
          inputs, Ut, Bm, RR, Nn, Nn / 4, nullptr, p1, nullptr);
  // xus = bf16((sum p1) * (S + sum p0))
  reduce_mul_kernel<<<Bm * RR / 4 / 256, 256, 0, stream>>>(p1, p0, S, xus, Bm * RR);
  // out = relu(xus @ V^T + b)  (M=2048, N=4096, K=512; B = V f32 fused-cvt)
  gemm_bt_kernel<4, 4, 2, false, true>
      <<<dim3((Bm / 128) * (UU / 128), 1), 256, 0, stream>>>(
          xus, V, Bm, UU, RR, RR, bias, out, nullptr);
}

// Round 4
// 66.061 us; speedup vs baseline: 1.5044x; 1.0379x over previous
//
#include <hip/hip_runtime.h>
#include <hip/hip_bf16.h>

typedef __attribute__((ext_vector_type(8))) __bf16 bf16x8;
typedef __attribute__((ext_vector_type(4))) float f32x4;
typedef __attribute__((ext_vector_type(8))) unsigned short ushort8;
typedef __attribute__((ext_vector_type(4))) unsigned short ushort4v;

__device__ __forceinline__ unsigned short f2bf(float f) {
  unsigned u = __builtin_bit_cast(unsigned, f);
  u += 0x7FFFu + ((u >> 16) & 1u);   // round-to-nearest-even
  return (unsigned short)(u >> 16);
}

__device__ __forceinline__ void gload_lds16(const void* g, void* l) {
  __builtin_amdgcn_global_load_lds(
      (const __attribute__((address_space(1))) void*)g,
      (__attribute__((address_space(3))) void*)l, 16, 0, 0);
}

// ---- prep: Ut = bf16(U^T), Wt = bf16(W^T), Vb = bf16(V), one launch ----
// U[4096][512] -> Ut[512][4096]   blocks [0, 2048)
// W[1024][512] -> Wt[512][1024]   blocks [2048, 2560)
// V (2M f32)  -> Vb bf16          blocks [2560, 3584)
__global__ __launch_bounds__(256) void prep_kernel(
    const float* __restrict__ U, unsigned short* __restrict__ Ut,
    const float* __restrict__ W, unsigned short* __restrict__ Wt,
    const float* __restrict__ V, unsigned short* __restrict__ Vb) {
  __shared__ float tile[32][33];
  const int b = blockIdx.x;
  const int tid = threadIdx.x;
  if (b < 2560) {
    const float* src;
    unsigned short* dst;
    int rows, cols, bx, by;
    if (b < 2048) {
      src = U; dst = Ut; rows = 4096; cols = 512;
      bx = (b & 15) * 32; by = (b >> 4) * 32;
    } else {
      int bb = b - 2048;
      src = W; dst = Wt; rows = 1024; cols = 512;
      bx = (bb & 15) * 32; by = (bb >> 4) * 32;
    }
    const int tx = tid & 31, ty = tid >> 5;
    for (int i = ty; i < 32; i += 8)
      tile[i][tx] = src[(size_t)(by + i) * cols + bx + tx];
    __syncthreads();
    for (int i = ty; i < 32; i += 8)
      dst[(size_t)(bx + i) * rows + by + tx] = f2bf(tile[tx][i]);
  } else {
    const size_t i = (size_t)(b - 2560) * 256 + tid;  // 8 f32 per thread
    const float4* s4 = reinterpret_cast<const float4*>(V) + 2 * i;
    float4 a = s4[0], c = s4[1];
    ushort8 o;
    o[0] = f2bf(a.x); o[1] = f2bf(a.y); o[2] = f2bf(a.z); o[3] = f2bf(a.w);
    o[4] = f2bf(c.x); o[5] = f2bf(c.y); o[6] = f2bf(c.z); o[7] = f2bf(c.w);
    *(reinterpret_cast<ushort8*>(Vb) + i) = o;
  }
}

// ---------------- bf16 GEMM core: C[*,N] tile = A[*,K] * Bt[N,K]^T ----------
// 2-phase double-buffered pipeline, one barrier per K-step.
// A is f32 (reg-staged, fused cvt: loads before MFMA, ds_write after) when
// AF32, else bf16 via global_load_lds. B always bf16 via global_load_lds.
// EPI 2: outf[idx] = relu(acc + e0[col]); EPI 3: outf[idx] = acc (partial).
template <int FM, int FN, int EPI, bool AF32>
__device__ __forceinline__ void gemm_core(
    const void* __restrict__ Av, const unsigned short* __restrict__ Bt,
    int N, int lda, int kchunk, int k0, const float* __restrict__ e0,
    float* __restrict__ outf) {
  constexpr int BM = 32 * FM, BN = 32 * FN, BK = 64;
  constexpr int AI = BM / 32, BI = BN / 32;  // 1KB staging issues per wave
  __shared__ unsigned short lds[2][(BM + BN) * BK];

  const int tid = threadIdx.x;
  const int wid = tid >> 6;
  const int lane = tid & 63;
  const int wr = wid >> 1, wc = wid & 1;

  // XCD-aware bijective swizzle (gridDim.x % 8 == 0 for all our grids)
  const int nwg = gridDim.x;
  const int bid = (int)blockIdx.x;
  const int swz = (bid & 7) * (nwg >> 3) + (bid >> 3);

  const int nbn = N / BN;
  const int brow = (swz / nbn) * BM;
  const int bcol = (swz % nbn) * BN;

  f32x4 zero = {0.f, 0.f, 0.f, 0.f};
  f32x4 acc[FM][FN];
#pragma unroll
  for (int m = 0; m < FM; ++m)
#pragma unroll
    for (int n = 0; n < FN; ++n) acc[m][n] = zero;

  // staging: each issue = 8 rows x 64 bf16 = 1KB, linear LDS.
  // XOR swizzle: physical chunk c at row r holds logical chunk c^(r&7);
  // source col pre-swizzled, read side applies ^(row&7).
  const int lr = lane >> 3;
  const int swzc = ((lane & 7) ^ lr) * 8;
  const size_t arow = (size_t)(brow + wid * (BM / 4) + lr);
  const size_t brw = (size_t)(bcol + wid * (BN / 4) + lr);
  const float* Agf = (const float*)Av + arow * lda + swzc + k0;
  const unsigned short* Agh = (const unsigned short*)Av + arow * lda + swzc + k0;
  const unsigned short* Bgh = Bt + brw * lda + swzc + k0;

  const int frow = lane & 15;
  const int fhi = lane >> 4;
  const int fx = lane & 7;

  const int nsteps = kchunk / BK;

  float4 areg[AI][2];

  auto stage_issue = [&](int b, int kofs) {
    if constexpr (AF32) {
#pragma unroll
      for (int i = 0; i < AI; ++i) {
        const float* s = Agf + kofs + (size_t)i * 8 * lda;
        areg[i][0] = *reinterpret_cast<const float4*>(s);
        areg[i][1] = *reinterpret_cast<const float4*>(s + 4);
      }
    } else {
      unsigned short* AsW = lds[b] + wid * (BM / 4) * 64;
#pragma unroll
      for (int i = 0; i < AI; ++i)
        gload_lds16(Agh + kofs + (size_t)i * 8 * lda, AsW + i * 512);
    }
    unsigned short* BsW = lds[b] + BM * BK + wid * (BN / 4) * 64;
#pragma unroll
    for (int i = 0; i < BI; ++i)
      gload_lds16(Bgh + kofs + (size_t)i * 8 * lda, BsW + i * 512);
  };

  auto stage_write = [&](int b) {
    if constexpr (AF32) {
      unsigned short* AsW = lds[b] + wid * (BM / 4) * 64 + lane * 8;
#pragma unroll
      for (int i = 0; i < AI; ++i) {
        float4 x = areg[i][0], y = areg[i][1];
        ushort8 o;
        o[0] = f2bf(x.x); o[1] = f2bf(x.y); o[2] = f2bf(x.z); o[3] = f2bf(x.w);
        o[4] = f2bf(y.x); o[5] = f2bf(y.y); o[6] = f2bf(y.z); o[7] = f2bf(y.w);
        *reinterpret_cast<ushort8*>(AsW + i * 512) = o;
      }
    }
  };

  stage_issue(0, 0);
  stage_write(0);
  __syncthreads();  // implicit vmcnt(0)+lgkmcnt(0) drain

  int cur = 0;
  for (int t = 0; t < nsteps; ++t) {
    bool has_next = (t + 1 < nsteps);
    if (has_next) stage_issue(cur ^ 1, (t + 1) * BK);  // in flight during MFMA
    const unsigned short* As = lds[cur];
    const unsigned short* Bs = lds[cur] + BM * BK;
#pragma unroll
    for (int ks = 0; ks < 2; ++ks) {
      bf16x8 af[FM], bg[FN];
#pragma unroll
      for (int m = 0; m < FM; ++m) {
        int row = wr * FM * 16 + m * 16 + frow;
        int c = (ks * 4 + fhi) ^ fx;
        af[m] = *reinterpret_cast<const bf16x8*>(As + row * 64 + c * 8);
      }
#pragma unroll
      for (int n = 0; n < FN; ++n) {
        int row = wc * FN * 16 + n * 16 + frow;
        int c = (ks * 4 + fhi) ^ fx;
        bg[n] = *reinterpret_cast<const bf16x8*>(Bs + row * 64 + c * 8);
      }
#pragma unroll
      for (int m = 0; m < FM; ++m)
#pragma unroll
        for (int n = 0; n < FN; ++n)
          acc[m][n] = __builtin_amdgcn_mfma_f32_16x16x32_bf16(af[m], bg[n],
                                                              acc[m][n], 0, 0, 0);
    }
    if (has_next) stage_write(cur ^ 1);  // cvt+ds_write after MFMA hid latency
    __syncthreads();
    cur ^= 1;
  }

  // epilogue: D col = lane&15, row = (lane>>4)*4 + j
#pragma unroll
  for (int m = 0; m < FM; ++m) {
    int gr0 = brow + wr * FM * 16 + m * 16 + fhi * 4;
#pragma unroll
    for (int n = 0; n < FN; ++n) {
      int gc = bcol + wc * FN * 16 + n * 16 + frow;
#pragma unroll
      for (int j = 0; j < 4; ++j) {
        size_t idx = (size_t)(gr0 + j) * N + gc;
        float v = acc[m][n][j];
        if constexpr (EPI == 2) {
          v += e0[gc];
          outf[idx] = v > 0.f ? v : 0.f;
        } else {
          outf[idx] = v;
        }
      }
    }
  }
}

// ---- merged split-K partial GEMMs: y<2 -> context@W, y>=2 -> inputs@U ----
__global__ __launch_bounds__(256) void gemm01_kernel(
    const float* __restrict__ ctx, const unsigned short* __restrict__ Wt,
    const float* __restrict__ inp, const unsigned short* __restrict__ Ut,
    float* __restrict__ p0, float* __restrict__ p1) {
  const int y = blockIdx.y;
  const float* A;
  const unsigned short* Bt;
  int lda, kchunk, k0;
  float* outp;
  if (y < 2) {
    A = ctx; Bt = Wt; lda = 1024; kchunk = 512; k0 = y * 512;
    outp = p0 + (size_t)y * 2048 * 512;
  } else {
    A = inp; Bt = Ut; lda = 4096; kchunk = 1024; k0 = (y - 2) * 1024;
    outp = p1 + (size_t)(y - 2) * 2048 * 512;
  }
  gemm_core<2, 2, 3, true>(A, Bt, 512, lda, kchunk, k0, nullptr, outp);
}

// ---- final GEMM: out = relu(xus @ V^T + bias), all-bf16 ----
__global__ __launch_bounds__(256) void gemm2_kernel(
    const unsigned short* __restrict__ xus, const unsigned short* __restrict__ Vb,
    const float* __restrict__ bias, float* __restrict__ out) {
  gemm_core<2, 4, 2, false>(xus, Vb, 4096, 512, 512, 0, bias, out);
}

// ---- fused split-K reduce: xus = bf16((sum p1) * (S + sum p0)) ----
__global__ void reduce_mul_kernel(const float* __restrict__ p1,  // [4][MN]
                                  const float* __restrict__ p0,  // [2][MN]
                                  const float* __restrict__ Svec,  // [512]
                                  unsigned short* __restrict__ xus, int MN) {
  int i = blockIdx.x * blockDim.x + threadIdx.x;
  size_t base = (size_t)i * 4;
  if (base >= (size_t)MN) return;
  float4 a = *reinterpret_cast<const float4*>(p1 + base);
  float4 b = *reinterpret_cast<const float4*>(p1 + (size_t)MN + base);
  float4 c = *reinterpret_cast<const float4*>(p1 + 2 * (size_t)MN + base);
  float4 d = *reinterpret_cast<const float4*>(p1 + 3 * (size_t)MN + base);
  float4 s0 = *reinterpret_cast<const float4*>(p0 + base);
  float4 s1 = *reinterpret_cast<const float4*>(p0 + (size_t)MN + base);
  float4 sv = *reinterpret_cast<const float4*>(Svec + (base & 511));
  float4 xu, s;
  xu.x = (a.x + b.x) + (c.x + d.x);  s.x = s0.x + s1.x + sv.x;
  xu.y = (a.y + b.y) + (c.y + d.y);  s.y = s0.y + s1.y + sv.y;
  xu.z = (a.z + b.z) + (c.z + d.z);  s.z = s0.z + s1.z + sv.z;
  xu.w = (a.w + b.w) + (c.w + d.w);  s.w = s0.w + s1.w + sv.w;
  ushort4v o;
  o[0] = f2bf(xu.x * s.x);
  o[1] = f2bf(xu.y * s.y);
  o[2] = f2bf(xu.z * s.z);
  o[3] = f2bf(xu.w * s.w);
  *reinterpret_cast<ushort4v*>(xus + base) = o;
}

extern "C" void kernel_launch(void* const* d_in, const int* in_sizes, int n_in,
                              void* d_out, int out_size, void* d_ws, size_t ws_size,
                              hipStream_t stream) {
  constexpr int Bm = 2048, Nn = 4096, Cc = 1024, UU = 4096, RR = 512;
  const float* inputs  = (const float*)d_in[0];
  const float* context = (const float*)d_in[1];
  const float* U       = (const float*)d_in[2];
  const float* S       = (const float*)d_in[3];
  const float* V       = (const float*)d_in[4];
  const float* W       = (const float*)d_in[5];
  const float* bias    = (const float*)d_in[6];
  float* out = (float*)d_out;

  char* p = (char*)d_ws;
  unsigned short* Ut  = (unsigned short*)p; p += (size_t)RR * Nn * 2;      //  4 MB
  unsigned short* Wt  = (unsigned short*)p; p += (size_t)RR * Cc * 2;      //  1 MB
  unsigned short* Vb  = (unsigned short*)p; p += (size_t)UU * RR * 2;      //  4 MB
  float*          p0  = (float*)p;          p += (size_t)2 * Bm * RR * 4;  //  8 MB
  float*          p1  = (float*)p;          p += (size_t)4 * Bm * RR * 4;  // 16 MB
  unsigned short* xus = (unsigned short*)p; p += (size_t)Bm * RR * 2;      //  2 MB

  // 1) prep: U^T, W^T, V -> bf16 in one launch
  prep_kernel<<<3584, 256, 0, stream>>>(U, Ut, W, Wt, V, Vb);

  // 2) merged split-K partials: p0[2] = context@W chunks, p1[4] = inputs@U chunks
  gemm01_kernel<<<dim3((Bm / 64) * (RR / 64), 6), 256, 0, stream>>>(
      context, Wt, inputs, Ut, p0, p1);

  // 3) xus = bf16((sum p1) * (S + sum p0))
  reduce_mul_kernel<<<Bm * RR / 4 / 256, 256, 0, stream>>>(p1, p0, S, xus, Bm * RR);

  // 4) out = relu(xus @ V^T + bias)   (M=2048, N=4096, K=512, 64x128 tile)
  gemm2_kernel<<<dim3((Bm / 64) * (UU / 128), 1), 256, 0, stream>>>(xus, Vb, bias, out);
}